// Round 13
// baseline (426.301 us; speedup 1.0000x reference)
//
#include <hip/hip_runtime.h>
#include <hip/hip_bf16.h>
#include <hip/hip_cooperative_groups.h>
#include <stdint.h>

namespace cg = cooperative_groups;

#define H 8
#define NQ 1024
#define NKV 8192
#define DM 256
#define DH 32
#define KVBLK 128
#define KSPLIT 8
#define QBLK 128
#define NITER (NKV / KSPLIT / KVBLK)   // 8
#define SCALE 0.17677669529663687f

typedef __attribute__((ext_vector_type(8))) __bf16 bf16x8;
typedef __attribute__((ext_vector_type(4))) float f32x4;

__device__ inline unsigned short f2bf(float f) {
  unsigned int u = __builtin_bit_cast(unsigned int, f);
  u = (u + 0x7FFFu + ((u >> 16) & 1u)) >> 16;
  return (unsigned short)u;
}

struct Params {
  const float *q, *kv, *bias, *Wq, *Wk, *Wv, *Wo, *gq, *bq, *gkv, *bkv;
  unsigned short *qn, *kvn, *Wqb, *Wkb, *Wvb, *Wob, *Qw, *Kw, *Vtw;
  float *Opart, *Mpart, *Lpart, *out;
};

// ---------------- phase 0: weight fp32->bf16 (blocks 0..31) + LayerNorm (32..175) ----------------
__device__ inline void phase0(int bx, int tid, const Params& p) {
  if (bx < 32) {
    long i = ((long)bx * 512 + tid) * 16;   // 262144 floats total over 4 weights
    int widx = (int)(i >> 16);
    int off = (int)(i & 65535);
    const float* src; unsigned short* dst;
    if (widx == 0)      { src = p.Wq; dst = p.Wqb; }
    else if (widx == 1) { src = p.Wk; dst = p.Wkb; }
    else if (widx == 2) { src = p.Wv; dst = p.Wvb; }
    else                { src = p.Wo; dst = p.Wob; }
#pragma unroll
    for (int j = 0; j < 4; j++) {
      float4 v = *(const float4*)(src + off + j * 4);
      unsigned int lo = (unsigned int)f2bf(v.x) | ((unsigned int)f2bf(v.y) << 16);
      unsigned int hi = (unsigned int)f2bf(v.z) | ((unsigned int)f2bf(v.w) << 16);
      *(uint2*)(dst + off + j * 4) = make_uint2(lo, hi);
    }
    return;
  }
  if (bx >= 176) return;
  int row = (bx - 32) * 128 + (tid >> 2);
  int l4 = tid & 3;
  const float* src; const float* ga; const float* be; unsigned short* dst;
  if (row < 2048) {
    src = p.q + (long)row * DM; ga = p.gq; be = p.bq; dst = p.qn + (long)row * DM;
  } else {
    int r2 = row - 2048;
    src = p.kv + (long)r2 * DM; ga = p.gkv; be = p.bkv; dst = p.kvn + (long)r2 * DM;
  }
  int c0 = l4 * 64;
  float s = 0.f, ss = 0.f;
  float4 xv[16];
#pragma unroll
  for (int i = 0; i < 16; i++) {
    float4 v = *(const float4*)(src + c0 + i * 4);
    xv[i] = v;
    s += v.x + v.y + v.z + v.w;
    ss += v.x * v.x + v.y * v.y + v.z * v.z + v.w * v.w;
  }
  s += __shfl_xor(s, 1, 4);  s += __shfl_xor(s, 2, 4);
  ss += __shfl_xor(ss, 1, 4); ss += __shfl_xor(ss, 2, 4);
  float mean = s * (1.0f / 256.0f);
  float var = ss * (1.0f / 256.0f) - mean * mean;
  float rs = 1.0f / sqrtf(var + 1e-5f);
#pragma unroll
  for (int i = 0; i < 8; i++) {
    float4 a = xv[2 * i], b = xv[2 * i + 1];
    float4 g0 = *(const float4*)(ga + c0 + i * 8);
    float4 g1 = *(const float4*)(ga + c0 + i * 8 + 4);
    float4 b0 = *(const float4*)(be + c0 + i * 8);
    float4 b1 = *(const float4*)(be + c0 + i * 8 + 4);
    unsigned short t[8];
    t[0] = f2bf((a.x - mean) * rs * g0.x + b0.x);
    t[1] = f2bf((a.y - mean) * rs * g0.y + b0.y);
    t[2] = f2bf((a.z - mean) * rs * g0.z + b0.z);
    t[3] = f2bf((a.w - mean) * rs * g0.w + b0.w);
    t[4] = f2bf((b.x - mean) * rs * g1.x + b1.x);
    t[5] = f2bf((b.y - mean) * rs * g1.y + b1.y);
    t[6] = f2bf((b.z - mean) * rs * g1.z + b1.z);
    t[7] = f2bf((b.w - mean) * rs * g1.w + b1.w);
    unsigned int u0 = (unsigned int)t[0] | ((unsigned int)t[1] << 16);
    unsigned int u1 = (unsigned int)t[2] | ((unsigned int)t[3] << 16);
    unsigned int u2 = (unsigned int)t[4] | ((unsigned int)t[5] << 16);
    unsigned int u3 = (unsigned int)t[6] | ((unsigned int)t[7] << 16);
    *(uint4*)(dst + c0 + i * 8) = make_uint4(u0, u1, u2, u3);
  }
}

// ---------------- phase 1: projections; unit in [0,544), t in [0,256) ----------------
__device__ inline void proj_unit(int unit, int t, const Params& p) {
  const unsigned short* X; const unsigned short* Wb; unsigned short* out;
  int Nper, mode, mb;
  if (unit < 32)       { X = p.qn;  Wb = p.Wqb; out = p.Qw;  Nper = NQ;  mode = 0; mb = unit; }
  else if (unit < 288) { X = p.kvn; Wb = p.Wkb; out = p.Kw;  Nper = NKV; mode = 0; mb = unit - 32; }
  else                 { X = p.kvn; Wb = p.Wvb; out = p.Vtw; Nper = NKV; mode = 1; mb = unit - 288; }

  int w = t >> 6, lane = t & 63;
  int c = lane & 15, g = lane >> 4;
  int mbase = mb * 64 + w * 16;
  f32x4 acc[16];
#pragma unroll
  for (int i = 0; i < 16; i++) acc[i] = (f32x4){0.f, 0.f, 0.f, 0.f};
  const unsigned short* arow = X + (long)(mbase + c) * DM + g * 8;
#pragma unroll
  for (int ks = 0; ks < 8; ks++) {
    bf16x8 af = *(const bf16x8*)(arow + ks * 32);
#pragma unroll
    for (int nt = 0; nt < 16; nt++) {
      bf16x8 bf = *(const bf16x8*)(Wb + (long)(nt * 16 + c) * DM + ks * 32 + g * 8);
      acc[nt] = __builtin_amdgcn_mfma_f32_16x16x32_bf16(af, bf, acc[nt], 0, 0, 0);
    }
  }
#pragma unroll
  for (int nt = 0; nt < 16; nt++) {
#pragma unroll
    for (int r = 0; r < 4; r++) {
      int m = mbase + 4 * g + r;
      int n = nt * 16 + c;
      int b = (m >= Nper) ? 1 : 0;
      int i = m - b * Nper;
      int h = n >> 5, dd = n & 31;
      long idx;
      if (mode == 0) idx = ((long)(b * H + h) * Nper + i) * DH + dd;
      else           idx = ((long)(b * H + h) * DH + dd) * (long)Nper + i;
      out[idx] = f2bf(acc[nt][r]);
    }
  }
}

// ---------------- phase 2: attention unit (R12 structure, QBLK=128, s-interleaved) ----------------
__device__ inline void attn_unit(int u, int tid, const Params& p) {
  __shared__ __align__(16) unsigned short Klds[KVBLK * 40];     // 10 KB
  __shared__ __align__(16) unsigned short Vlds[DH * 136];       // 8.5 KB
  __shared__ __align__(16) unsigned short Plds[8][16 * 136];    // 34.8 KB

  int s = u & 7, qt = (u >> 3) & 7, bh = u >> 6;
  int w = tid >> 6, lane = tid & 63, c = lane & 15, g = lane >> 4;

  const f32x4 fzero = {0.f, 0.f, 0.f, 0.f};

  bf16x8 qfrag = *(const bf16x8*)(p.Qw + ((long)(bh * NQ + qt * QBLK + w * 16 + c)) * DH + g * 8);

  const float* brow = p.bias + ((long)bh * NQ + qt * QBLK + w * 16 + c) * (long)NKV + 4 * g;

  const unsigned short* Kbase = p.Kw + ((long)bh * NKV) * DH;    // [k][32]
  const unsigned short* Vbase = p.Vtw + ((long)bh * DH) * NKV;   // [d][NKV]

  float m_run = -1e30f;   // per-lane, q = c
  float l_run = 0.f;
  f32x4 oacc[2] = {fzero, fzero};

#pragma unroll 1
  for (int it = 0; it < NITER; it++) {
    int k0 = (it * KSPLIT + s) * KVBLK;   // interleaved chunk assignment

    f32x4 bfrag[8];
#pragma unroll
    for (int t = 0; t < 8; t++)
      bfrag[t] = *(const f32x4*)(brow + k0 + t * 16);

    {
      int krow = tid >> 2, kq4 = tid & 3;
      *(uint4*)(&Klds[krow * 40 + kq4 * 8]) =
          *(const uint4*)(Kbase + (long)(k0 + krow) * DH + kq4 * 8);
      int vd = tid >> 4, vq16 = tid & 15;
      *(uint4*)(&Vlds[vd * 136 + vq16 * 8]) =
          *(const uint4*)(Vbase + (long)vd * NKV + k0 + vq16 * 8);
    }
    __syncthreads();

    // S^T = K Q^T  (8 k-subtiles of 16)
    f32x4 sacc[8];
#pragma unroll
    for (int t = 0; t < 8; t++) {
      bf16x8 kf = *(const bf16x8*)(&Klds[(t * 16 + c) * 40 + g * 8]);
      sacc[t] = __builtin_amdgcn_mfma_f32_16x16x32_bf16(kf, qfrag, fzero, 0, 0, 0);
    }
#pragma unroll
    for (int t = 0; t < 8; t++) {
#pragma unroll
      for (int r = 0; r < 4; r++)
        sacc[t][r] = fmaf(sacc[t][r], SCALE, bfrag[t][r]);
    }

    // online softmax, per-lane row q=c
    float v = -1e30f;
#pragma unroll
    for (int t = 0; t < 8; t++)
      v = fmaxf(v, fmaxf(fmaxf(sacc[t][0], sacc[t][1]), fmaxf(sacc[t][2], sacc[t][3])));
    v = fmaxf(v, __shfl_xor(v, 16));
    v = fmaxf(v, __shfl_xor(v, 32));
    float mnew = fmaxf(m_run, v);
    float al = __expf(m_run - mnew);
    m_run = mnew;
    float rsum = 0.f;
#pragma unroll
    for (int t = 0; t < 8; t++) {
      float p0 = __expf(sacc[t][0] - mnew);
      float p1 = __expf(sacc[t][1] - mnew);
      float p2 = __expf(sacc[t][2] - mnew);
      float p3 = __expf(sacc[t][3] - mnew);
      rsum += (p0 + p1) + (p2 + p3);
      uint2 pk;
      pk.x = (unsigned int)f2bf(p0) | ((unsigned int)f2bf(p1) << 16);
      pk.y = (unsigned int)f2bf(p2) | ((unsigned int)f2bf(p3) << 16);
      *(uint2*)(&Plds[w][c * 136 + t * 16 + 4 * g]) = pk;
    }
    rsum += __shfl_xor(rsum, 16);
    rsum += __shfl_xor(rsum, 32);
    l_run = l_run * al + rsum;

    float alq[4];
#pragma unroll
    for (int r = 0; r < 4; r++) alq[r] = __shfl(al, 4 * g + r);
#pragma unroll
    for (int r = 0; r < 4; r++) { oacc[0][r] *= alq[r]; oacc[1][r] *= alq[r]; }

    // O += P @ V  (4 k-chunks of 32, 2 d-tiles of 16)
#pragma unroll
    for (int ch = 0; ch < 4; ch++) {
      bf16x8 pf = *(const bf16x8*)(&Plds[w][c * 136 + ch * 32 + g * 8]);
#pragma unroll
      for (int dt = 0; dt < 2; dt++) {
        bf16x8 vf = *(const bf16x8*)(&Vlds[(dt * 16 + c) * 136 + ch * 32 + g * 8]);
        oacc[dt] = __builtin_amdgcn_mfma_f32_16x16x32_bf16(pf, vf, oacc[dt], 0, 0, 0);
      }
    }
    __syncthreads();
  }
  // write partials (128 rows per unit; row = w*16 + 4g+r, col = d)
  float* Op = p.Opart + (long)u * (QBLK * 32);
#pragma unroll
  for (int dt = 0; dt < 2; dt++)
#pragma unroll
    for (int r = 0; r < 4; r++)
      Op[(w * 16 + 4 * g + r) * 32 + dt * 16 + c] = oacc[dt][r];
  if (g == 0) {
    p.Mpart[(long)u * QBLK + w * 16 + c] = m_run;
    p.Lpart[(long)u * QBLK + w * 16 + c] = l_run;
  }
}

// ---------------- phase 3: merge + outproj + residual; bx in [0,128), 512 threads ----------------
__device__ inline void merge_unit(int bx, int tid, const Params& p) {
  __shared__ __align__(16) unsigned short OmT[16][264];

  int b = bx >> 6, t6 = bx & 63;
  int qt8 = t6 >> 3;
  int rbase = (t6 & 7) * 16;

  // phase 1: merge; 32 threads per row, 1 col each
  int row16 = tid >> 5;                 // [0,16)
  int dcol = tid & 31;                  // [0,32)
  int rowin = rbase + row16;
#pragma unroll 1
  for (int h = 0; h < 8; h++) {
    long pbase = (((long)(b * 8 + h) * 8 + qt8)) * 8;
    float mg = -1e30f, ms[8];
#pragma unroll
    for (int si = 0; si < 8; si++) {
      ms[si] = p.Mpart[(pbase + si) * QBLK + rowin];
      mg = fmaxf(mg, ms[si]);
    }
    float Lg = 0.f, o = 0.f;
#pragma unroll
    for (int si = 0; si < 8; si++) {
      float wsc = __expf(ms[si] - mg);
      Lg += p.Lpart[(pbase + si) * QBLK + rowin] * wsc;
      o += p.Opart[(pbase + si) * (QBLK * 32) + rowin * 32 + dcol] * wsc;
    }
    OmT[row16][h * 32 + dcol] = f2bf(o / Lg);
  }
  __syncthreads();

  // phase 2: outproj + residual; 8 waves x 32 cols each
  int w = tid >> 6, lane = tid & 63;
  int c = lane & 15, g = lane >> 4;
  long mglob = (long)b * NQ + t6 * 16;
  f32x4 acc[2];
  acc[0] = (f32x4){0.f, 0.f, 0.f, 0.f};
  acc[1] = (f32x4){0.f, 0.f, 0.f, 0.f};
#pragma unroll
  for (int ks = 0; ks < 8; ks++) {
    bf16x8 af = *(const bf16x8*)(&OmT[c][ks * 32 + g * 8]);
#pragma unroll
    for (int j = 0; j < 2; j++) {
      int nt = w * 2 + j;
      bf16x8 bf = *(const bf16x8*)(p.Wob + (long)(nt * 16 + c) * DM + ks * 32 + g * 8);
      acc[j] = __builtin_amdgcn_mfma_f32_16x16x32_bf16(af, bf, acc[j], 0, 0, 0);
    }
  }
#pragma unroll
  for (int j = 0; j < 2; j++) {
#pragma unroll
    for (int r = 0; r < 4; r++) {
      long m = mglob + 4 * g + r;
      int n = (w * 2 + j) * 16 + c;
      p.out[m * DM + n] = p.q[m * DM + n] + acc[j][r];
    }
  }
}

// ---------------- fused cooperative kernel: 512 blocks x 512 threads ----------------
__global__ __launch_bounds__(512, 4) void fused_kernel(Params p) {
  cg::grid_group grid = cg::this_grid();
  int bx = blockIdx.x, tid = threadIdx.x;

  phase0(bx, tid, p);
  grid.sync();

  if (bx < 272) proj_unit(bx * 2 + (tid >> 8), tid & 255, p);
  grid.sync();

  attn_unit(bx, tid, p);
  __syncthreads();
  attn_unit(bx + 512, tid, p);
  grid.sync();

  if (bx < 128) merge_unit(bx, tid, p);
}

// ---------------- fallback kernels (same device code, 4 dispatches) ----------------
__global__ __launch_bounds__(512, 4) void prep512_kernel(Params p) {
  phase0(blockIdx.x, threadIdx.x, p);
}
__global__ __launch_bounds__(512, 4) void proj512_kernel(Params p) {
  proj_unit(blockIdx.x * 2 + (threadIdx.x >> 8), threadIdx.x & 255, p);
}
__global__ __launch_bounds__(512, 4) void attn512_kernel(Params p) {
  attn_unit(blockIdx.x, threadIdx.x, p);
}
__global__ __launch_bounds__(512, 4) void merge512_kernel(Params p) {
  merge_unit(blockIdx.x, threadIdx.x, p);
}

extern "C" void kernel_launch(void* const* d_in, const int* in_sizes, int n_in,
                              void* d_out, int out_size, void* d_ws, size_t ws_size,
                              hipStream_t stream) {
  (void)in_sizes; (void)n_in; (void)out_size; (void)ws_size;

  char* ws = (char*)d_ws;
  size_t off = 0;
  auto alloc = [&](size_t bytes) -> void* {
    void* ptr = ws + off;
    off += (bytes + 255) & ~(size_t)255;
    return ptr;
  };

  Params p;
  p.q    = (const float*)d_in[0];
  p.kv   = (const float*)d_in[1];
  p.bias = (const float*)d_in[2];
  p.Wq   = (const float*)d_in[3];
  p.Wk   = (const float*)d_in[4];
  p.Wv   = (const float*)d_in[5];
  p.Wo   = (const float*)d_in[6];
  p.gq   = (const float*)d_in[7];
  p.bq   = (const float*)d_in[8];
  p.gkv  = (const float*)d_in[9];
  p.bkv  = (const float*)d_in[10];
  p.out  = (float*)d_out;

  p.Wqb  = (unsigned short*)alloc(65536 * 2);
  p.Wkb  = (unsigned short*)alloc(65536 * 2);
  p.Wvb  = (unsigned short*)alloc(65536 * 2);
  p.Wob  = (unsigned short*)alloc(65536 * 2);
  p.qn   = (unsigned short*)alloc((size_t)2048 * 256 * 2);
  p.kvn  = (unsigned short*)alloc((size_t)16384 * 256 * 2);
  p.Qw   = (unsigned short*)alloc((size_t)2048 * 256 * 2);
  p.Kw   = (unsigned short*)alloc((size_t)16384 * 256 * 2);
  p.Vtw  = (unsigned short*)alloc((size_t)16384 * 256 * 2);
  p.Opart = (float*)alloc((size_t)1024 * 128 * 32 * 4);
  p.Mpart = (float*)alloc((size_t)1024 * 128 * 4);
  p.Lpart = (float*)alloc((size_t)1024 * 128 * 4);

  void* kargs[] = { &p };
  hipError_t err = hipLaunchCooperativeKernel(
      reinterpret_cast<const void*>(fused_kernel),
      dim3(512), dim3(512), kargs, 0, stream);

  if (err != hipSuccess) {
    (void)hipGetLastError();   // clear error state; use proven 4-dispatch path
    prep512_kernel<<<176, 512, 0, stream>>>(p);
    proj512_kernel<<<272, 512, 0, stream>>>(p);
    attn512_kernel<<<1024, 512, 0, stream>>>(p);
    merge512_kernel<<<128, 512, 0, stream>>>(p);
  }
}

// Round 14
// 425.224 us; speedup vs baseline: 1.0025x; 1.0025x over previous
//
#include <hip/hip_runtime.h>
#include <hip/hip_bf16.h>
#include <hip/hip_cooperative_groups.h>
#include <stdint.h>

namespace cg = cooperative_groups;

#define H 8
#define NQ 1024
#define NKV 8192
#define DM 256
#define DH 32
#define KVBLK 128
#define KSPLIT 8
#define QBLK 128
#define NITER (NKV / KSPLIT / KVBLK)   // 8
#define SCALE 0.17677669529663687f

typedef __attribute__((ext_vector_type(8))) __bf16 bf16x8;
typedef __attribute__((ext_vector_type(4))) float f32x4;

__device__ inline unsigned short f2bf(float f) {
  unsigned int u = __builtin_bit_cast(unsigned int, f);
  u = (u + 0x7FFFu + ((u >> 16) & 1u)) >> 16;
  return (unsigned short)u;
}

struct Params {
  const float *q, *kv, *bias, *Wq, *Wk, *Wv, *Wo, *gq, *bq, *gkv, *bkv;
  unsigned short *qn, *kvn, *Wqb, *Wkb, *Wvb, *Wob, *Qw, *Kw, *Vtw;
  float *Opart, *Mpart, *Lpart, *out;
};

// ---------------- phase 0: weight fp32->bf16 (blocks 0..31) + LayerNorm (32..175) ----------------
__device__ inline void phase0(int bx, int tid, const Params& p) {
  if (bx < 32) {
    long i = ((long)bx * 512 + tid) * 16;   // 262144 floats total over 4 weights
    int widx = (int)(i >> 16);
    int off = (int)(i & 65535);
    const float* src; unsigned short* dst;
    if (widx == 0)      { src = p.Wq; dst = p.Wqb; }
    else if (widx == 1) { src = p.Wk; dst = p.Wkb; }
    else if (widx == 2) { src = p.Wv; dst = p.Wvb; }
    else                { src = p.Wo; dst = p.Wob; }
#pragma unroll
    for (int j = 0; j < 4; j++) {
      float4 v = *(const float4*)(src + off + j * 4);
      unsigned int lo = (unsigned int)f2bf(v.x) | ((unsigned int)f2bf(v.y) << 16);
      unsigned int hi = (unsigned int)f2bf(v.z) | ((unsigned int)f2bf(v.w) << 16);
      *(uint2*)(dst + off + j * 4) = make_uint2(lo, hi);
    }
    return;
  }
  if (bx >= 176) return;
  int row = (bx - 32) * 128 + (tid >> 2);
  int l4 = tid & 3;
  const float* src; const float* ga; const float* be; unsigned short* dst;
  if (row < 2048) {
    src = p.q + (long)row * DM; ga = p.gq; be = p.bq; dst = p.qn + (long)row * DM;
  } else {
    int r2 = row - 2048;
    src = p.kv + (long)r2 * DM; ga = p.gkv; be = p.bkv; dst = p.kvn + (long)r2 * DM;
  }
  int c0 = l4 * 64;
  float s = 0.f, ss = 0.f;
  float4 xv[16];
#pragma unroll
  for (int i = 0; i < 16; i++) {
    float4 v = *(const float4*)(src + c0 + i * 4);
    xv[i] = v;
    s += v.x + v.y + v.z + v.w;
    ss += v.x * v.x + v.y * v.y + v.z * v.z + v.w * v.w;
  }
  s += __shfl_xor(s, 1, 4);  s += __shfl_xor(s, 2, 4);
  ss += __shfl_xor(ss, 1, 4); ss += __shfl_xor(ss, 2, 4);
  float mean = s * (1.0f / 256.0f);
  float var = ss * (1.0f / 256.0f) - mean * mean;
  float rs = 1.0f / sqrtf(var + 1e-5f);
#pragma unroll
  for (int i = 0; i < 8; i++) {
    float4 a = xv[2 * i], b = xv[2 * i + 1];
    float4 g0 = *(const float4*)(ga + c0 + i * 8);
    float4 g1 = *(const float4*)(ga + c0 + i * 8 + 4);
    float4 b0 = *(const float4*)(be + c0 + i * 8);
    float4 b1 = *(const float4*)(be + c0 + i * 8 + 4);
    unsigned short t[8];
    t[0] = f2bf((a.x - mean) * rs * g0.x + b0.x);
    t[1] = f2bf((a.y - mean) * rs * g0.y + b0.y);
    t[2] = f2bf((a.z - mean) * rs * g0.z + b0.z);
    t[3] = f2bf((a.w - mean) * rs * g0.w + b0.w);
    t[4] = f2bf((b.x - mean) * rs * g1.x + b1.x);
    t[5] = f2bf((b.y - mean) * rs * g1.y + b1.y);
    t[6] = f2bf((b.z - mean) * rs * g1.z + b1.z);
    t[7] = f2bf((b.w - mean) * rs * g1.w + b1.w);
    unsigned int u0 = (unsigned int)t[0] | ((unsigned int)t[1] << 16);
    unsigned int u1 = (unsigned int)t[2] | ((unsigned int)t[3] << 16);
    unsigned int u2 = (unsigned int)t[4] | ((unsigned int)t[5] << 16);
    unsigned int u3 = (unsigned int)t[6] | ((unsigned int)t[7] << 16);
    *(uint4*)(dst + c0 + i * 8) = make_uint4(u0, u1, u2, u3);
  }
}

// ---------------- phase 1: projections; unit in [0,544), t in [0,256) ----------------
__device__ inline void proj_unit(int unit, int t, const Params& p) {
  const unsigned short* X; const unsigned short* Wb; unsigned short* out;
  int Nper, mode, mb;
  if (unit < 32)       { X = p.qn;  Wb = p.Wqb; out = p.Qw;  Nper = NQ;  mode = 0; mb = unit; }
  else if (unit < 288) { X = p.kvn; Wb = p.Wkb; out = p.Kw;  Nper = NKV; mode = 0; mb = unit - 32; }
  else                 { X = p.kvn; Wb = p.Wvb; out = p.Vtw; Nper = NKV; mode = 1; mb = unit - 288; }

  int w = t >> 6, lane = t & 63;
  int c = lane & 15, g = lane >> 4;
  int mbase = mb * 64 + w * 16;
  f32x4 acc[16];
#pragma unroll
  for (int i = 0; i < 16; i++) acc[i] = (f32x4){0.f, 0.f, 0.f, 0.f};
  const unsigned short* arow = X + (long)(mbase + c) * DM + g * 8;
#pragma unroll
  for (int ks = 0; ks < 8; ks++) {
    bf16x8 af = *(const bf16x8*)(arow + ks * 32);
#pragma unroll
    for (int nt = 0; nt < 16; nt++) {
      bf16x8 bf = *(const bf16x8*)(Wb + (long)(nt * 16 + c) * DM + ks * 32 + g * 8);
      acc[nt] = __builtin_amdgcn_mfma_f32_16x16x32_bf16(af, bf, acc[nt], 0, 0, 0);
    }
  }
#pragma unroll
  for (int nt = 0; nt < 16; nt++) {
#pragma unroll
    for (int r = 0; r < 4; r++) {
      int m = mbase + 4 * g + r;
      int n = nt * 16 + c;
      int b = (m >= Nper) ? 1 : 0;
      int i = m - b * Nper;
      int h = n >> 5, dd = n & 31;
      long idx;
      if (mode == 0) idx = ((long)(b * H + h) * Nper + i) * DH + dd;
      else           idx = ((long)(b * H + h) * DH + dd) * (long)Nper + i;
      out[idx] = f2bf(acc[nt][r]);
    }
  }
}

// ---------------- phase 2: attention unit (R12 structure, QBLK=128, s-interleaved) ----------------
__device__ inline void attn_unit(int u, int tid, const Params& p) {
  __shared__ __align__(16) unsigned short Klds[KVBLK * 40];     // 10 KB
  __shared__ __align__(16) unsigned short Vlds[DH * 136];       // 8.5 KB
  __shared__ __align__(16) unsigned short Plds[8][16 * 136];    // 34.8 KB

  int s = u & 7, qt = (u >> 3) & 7, bh = u >> 6;
  int w = tid >> 6, lane = tid & 63, c = lane & 15, g = lane >> 4;

  const f32x4 fzero = {0.f, 0.f, 0.f, 0.f};

  bf16x8 qfrag = *(const bf16x8*)(p.Qw + ((long)(bh * NQ + qt * QBLK + w * 16 + c)) * DH + g * 8);

  const float* brow = p.bias + ((long)bh * NQ + qt * QBLK + w * 16 + c) * (long)NKV + 4 * g;

  const unsigned short* Kbase = p.Kw + ((long)bh * NKV) * DH;    // [k][32]
  const unsigned short* Vbase = p.Vtw + ((long)bh * DH) * NKV;   // [d][NKV]

  float m_run = -1e30f;   // per-lane, q = c
  float l_run = 0.f;
  f32x4 oacc[2] = {fzero, fzero};

#pragma unroll 1
  for (int it = 0; it < NITER; it++) {
    int k0 = (it * KSPLIT + s) * KVBLK;   // interleaved chunk assignment

    f32x4 bfrag[8];
#pragma unroll
    for (int t = 0; t < 8; t++)
      bfrag[t] = *(const f32x4*)(brow + k0 + t * 16);

    {
      int krow = tid >> 2, kq4 = tid & 3;
      *(uint4*)(&Klds[krow * 40 + kq4 * 8]) =
          *(const uint4*)(Kbase + (long)(k0 + krow) * DH + kq4 * 8);
      int vd = tid >> 4, vq16 = tid & 15;
      *(uint4*)(&Vlds[vd * 136 + vq16 * 8]) =
          *(const uint4*)(Vbase + (long)vd * NKV + k0 + vq16 * 8);
    }
    __syncthreads();

    // S^T = K Q^T  (8 k-subtiles of 16)
    f32x4 sacc[8];
#pragma unroll
    for (int t = 0; t < 8; t++) {
      bf16x8 kf = *(const bf16x8*)(&Klds[(t * 16 + c) * 40 + g * 8]);
      sacc[t] = __builtin_amdgcn_mfma_f32_16x16x32_bf16(kf, qfrag, fzero, 0, 0, 0);
    }
#pragma unroll
    for (int t = 0; t < 8; t++) {
#pragma unroll
      for (int r = 0; r < 4; r++)
        sacc[t][r] = fmaf(sacc[t][r], SCALE, bfrag[t][r]);
    }

    // online softmax, per-lane row q=c
    float v = -1e30f;
#pragma unroll
    for (int t = 0; t < 8; t++)
      v = fmaxf(v, fmaxf(fmaxf(sacc[t][0], sacc[t][1]), fmaxf(sacc[t][2], sacc[t][3])));
    v = fmaxf(v, __shfl_xor(v, 16));
    v = fmaxf(v, __shfl_xor(v, 32));
    float mnew = fmaxf(m_run, v);
    float al = __expf(m_run - mnew);
    m_run = mnew;
    float rsum = 0.f;
#pragma unroll
    for (int t = 0; t < 8; t++) {
      float p0 = __expf(sacc[t][0] - mnew);
      float p1 = __expf(sacc[t][1] - mnew);
      float p2 = __expf(sacc[t][2] - mnew);
      float p3 = __expf(sacc[t][3] - mnew);
      rsum += (p0 + p1) + (p2 + p3);
      uint2 pk;
      pk.x = (unsigned int)f2bf(p0) | ((unsigned int)f2bf(p1) << 16);
      pk.y = (unsigned int)f2bf(p2) | ((unsigned int)f2bf(p3) << 16);
      *(uint2*)(&Plds[w][c * 136 + t * 16 + 4 * g]) = pk;
    }
    rsum += __shfl_xor(rsum, 16);
    rsum += __shfl_xor(rsum, 32);
    l_run = l_run * al + rsum;

    float alq[4];
#pragma unroll
    for (int r = 0; r < 4; r++) alq[r] = __shfl(al, 4 * g + r);
#pragma unroll
    for (int r = 0; r < 4; r++) { oacc[0][r] *= alq[r]; oacc[1][r] *= alq[r]; }

    // O += P @ V  (4 k-chunks of 32, 2 d-tiles of 16)
#pragma unroll
    for (int ch = 0; ch < 4; ch++) {
      bf16x8 pf = *(const bf16x8*)(&Plds[w][c * 136 + ch * 32 + g * 8]);
#pragma unroll
      for (int dt = 0; dt < 2; dt++) {
        bf16x8 vf = *(const bf16x8*)(&Vlds[(dt * 16 + c) * 136 + ch * 32 + g * 8]);
        oacc[dt] = __builtin_amdgcn_mfma_f32_16x16x32_bf16(pf, vf, oacc[dt], 0, 0, 0);
      }
    }
    __syncthreads();
  }
  // write partials (128 rows per unit; row = w*16 + 4g+r, col = d)
  float* Op = p.Opart + (long)u * (QBLK * 32);
#pragma unroll
  for (int dt = 0; dt < 2; dt++)
#pragma unroll
    for (int r = 0; r < 4; r++)
      Op[(w * 16 + 4 * g + r) * 32 + dt * 16 + c] = oacc[dt][r];
  if (g == 0) {
    p.Mpart[(long)u * QBLK + w * 16 + c] = m_run;
    p.Lpart[(long)u * QBLK + w * 16 + c] = l_run;
  }
}

// ---------------- phase 3: merge + outproj + residual; bx in [0,128), 512 threads ----------------
__device__ inline void merge_unit(int bx, int tid, const Params& p) {
  __shared__ __align__(16) unsigned short OmT[16][264];

  int b = bx >> 6, t6 = bx & 63;
  int qt8 = t6 >> 3;
  int rbase = (t6 & 7) * 16;

  // phase 1: merge; 32 threads per row, 1 col each
  int row16 = tid >> 5;                 // [0,16)
  int dcol = tid & 31;                  // [0,32)
  int rowin = rbase + row16;
#pragma unroll 1
  for (int h = 0; h < 8; h++) {
    long pbase = (((long)(b * 8 + h) * 8 + qt8)) * 8;
    float mg = -1e30f, ms[8];
#pragma unroll
    for (int si = 0; si < 8; si++) {
      ms[si] = p.Mpart[(pbase + si) * QBLK + rowin];
      mg = fmaxf(mg, ms[si]);
    }
    float Lg = 0.f, o = 0.f;
#pragma unroll
    for (int si = 0; si < 8; si++) {
      float wsc = __expf(ms[si] - mg);
      Lg += p.Lpart[(pbase + si) * QBLK + rowin] * wsc;
      o += p.Opart[(pbase + si) * (QBLK * 32) + rowin * 32 + dcol] * wsc;
    }
    OmT[row16][h * 32 + dcol] = f2bf(o / Lg);
  }
  __syncthreads();

  // phase 2: outproj + residual; 8 waves x 32 cols each
  int w = tid >> 6, lane = tid & 63;
  int c = lane & 15, g = lane >> 4;
  long mglob = (long)b * NQ + t6 * 16;
  f32x4 acc[2];
  acc[0] = (f32x4){0.f, 0.f, 0.f, 0.f};
  acc[1] = (f32x4){0.f, 0.f, 0.f, 0.f};
#pragma unroll
  for (int ks = 0; ks < 8; ks++) {
    bf16x8 af = *(const bf16x8*)(&OmT[c][ks * 32 + g * 8]);
#pragma unroll
    for (int j = 0; j < 2; j++) {
      int nt = w * 2 + j;
      bf16x8 bf = *(const bf16x8*)(p.Wob + (long)(nt * 16 + c) * DM + ks * 32 + g * 8);
      acc[j] = __builtin_amdgcn_mfma_f32_16x16x32_bf16(af, bf, acc[j], 0, 0, 0);
    }
  }
#pragma unroll
  for (int j = 0; j < 2; j++) {
#pragma unroll
    for (int r = 0; r < 4; r++) {
      long m = mglob + 4 * g + r;
      int n = (w * 2 + j) * 16 + c;
      p.out[m * DM + n] = p.q[m * DM + n] + acc[j][r];
    }
  }
}

// ---------------- fused cooperative kernel: 512 blocks x 512 threads ----------------
// amdgpu_waves_per_eu(4,4): occupancy is LDS-capped at 2 blocks/CU = 4 waves/SIMD
// anyway, so cap the allocator's occupancy target and let it use up to 128 VGPRs
// (R13's allocator chose 64 -> spill/serialize -> 442 us).
__global__ __launch_bounds__(512) __attribute__((amdgpu_waves_per_eu(4, 4)))
void fused_kernel(Params p) {
  cg::grid_group grid = cg::this_grid();
  int bx = blockIdx.x, tid = threadIdx.x;

  phase0(bx, tid, p);
  grid.sync();

  if (bx < 272) proj_unit(bx * 2 + (tid >> 8), tid & 255, p);
  grid.sync();

  attn_unit(bx, tid, p);
  __syncthreads();
  attn_unit(bx + 512, tid, p);
  grid.sync();

  if (bx < 128) merge_unit(bx, tid, p);
}

// ---------------- fallback kernels (same device code, 4 dispatches) ----------------
__global__ __launch_bounds__(512) __attribute__((amdgpu_waves_per_eu(4, 4)))
void prep512_kernel(Params p) {
  phase0(blockIdx.x, threadIdx.x, p);
}
__global__ __launch_bounds__(512) __attribute__((amdgpu_waves_per_eu(4, 4)))
void proj512_kernel(Params p) {
  proj_unit(blockIdx.x * 2 + (threadIdx.x >> 8), threadIdx.x & 255, p);
}
__global__ __launch_bounds__(512) __attribute__((amdgpu_waves_per_eu(4, 4)))
void attn512_kernel(Params p) {
  attn_unit(blockIdx.x, threadIdx.x, p);
}
__global__ __launch_bounds__(512) __attribute__((amdgpu_waves_per_eu(4, 4)))
void merge512_kernel(Params p) {
  merge_unit(blockIdx.x, threadIdx.x, p);
}

extern "C" void kernel_launch(void* const* d_in, const int* in_sizes, int n_in,
                              void* d_out, int out_size, void* d_ws, size_t ws_size,
                              hipStream_t stream) {
  (void)in_sizes; (void)n_in; (void)out_size; (void)ws_size;

  char* ws = (char*)d_ws;
  size_t off = 0;
  auto alloc = [&](size_t bytes) -> void* {
    void* ptr = ws + off;
    off += (bytes + 255) & ~(size_t)255;
    return ptr;
  };

  Params p;
  p.q    = (const float*)d_in[0];
  p.kv   = (const float*)d_in[1];
  p.bias = (const float*)d_in[2];
  p.Wq   = (const float*)d_in[3];
  p.Wk   = (const float*)d_in[4];
  p.Wv   = (const float*)d_in[5];
  p.Wo   = (const float*)d_in[6];
  p.gq   = (const float*)d_in[7];
  p.bq   = (const float*)d_in[8];
  p.gkv  = (const float*)d_in[9];
  p.bkv  = (const float*)d_in[10];
  p.out  = (float*)d_out;

  p.Wqb  = (unsigned short*)alloc(65536 * 2);
  p.Wkb  = (unsigned short*)alloc(65536 * 2);
  p.Wvb  = (unsigned short*)alloc(65536 * 2);
  p.Wob  = (unsigned short*)alloc(65536 * 2);
  p.qn   = (unsigned short*)alloc((size_t)2048 * 256 * 2);
  p.kvn  = (unsigned short*)alloc((size_t)16384 * 256 * 2);
  p.Qw   = (unsigned short*)alloc((size_t)2048 * 256 * 2);
  p.Kw   = (unsigned short*)alloc((size_t)16384 * 256 * 2);
  p.Vtw  = (unsigned short*)alloc((size_t)16384 * 256 * 2);
  p.Opart = (float*)alloc((size_t)1024 * 128 * 32 * 4);
  p.Mpart = (float*)alloc((size_t)1024 * 128 * 4);
  p.Lpart = (float*)alloc((size_t)1024 * 128 * 4);

  void* kargs[] = { &p };
  hipError_t err = hipLaunchCooperativeKernel(
      reinterpret_cast<const void*>(fused_kernel),
      dim3(512), dim3(512), kargs, 0, stream);

  if (err != hipSuccess) {
    (void)hipGetLastError();   // clear error state; use proven 4-dispatch path
    prep512_kernel<<<176, 512, 0, stream>>>(p);
    proj512_kernel<<<272, 512, 0, stream>>>(p);
    attn512_kernel<<<1024, 512, 0, stream>>>(p);
    merge512_kernel<<<128, 512, 0, stream>>>(p);
  }
}

// Round 15
// 231.288 us; speedup vs baseline: 1.8432x; 1.8385x over previous
//
#include <hip/hip_runtime.h>
#include <hip/hip_bf16.h>
#include <stdint.h>

#define H 8
#define NQ 1024
#define NKV 8192
#define DM 256
#define DH 32
#define KVBLK 128
#define KSPLIT 8
#define QBLK 128
#define NITER (NKV / KSPLIT / KVBLK)   // 8
#define SCALE 0.17677669529663687f

typedef __attribute__((ext_vector_type(8))) __bf16 bf16x8;
typedef __attribute__((ext_vector_type(4))) float f32x4;

__device__ inline unsigned short f2bf(float f) {
  unsigned int u = __builtin_bit_cast(unsigned int, f);
  u = (u + 0x7FFFu + ((u >> 16) & 1u)) >> 16;
  return (unsigned short)u;
}

// ---------------- prep: weights fp32->bf16 (4x) + LayerNorm, one dispatch ----------------
__global__ void prep_kernel(const float* __restrict__ q, const float* __restrict__ kv,
                            const float* __restrict__ gq, const float* __restrict__ bq,
                            const float* __restrict__ gkv, const float* __restrict__ bkv,
                            const float* __restrict__ Wq, const float* __restrict__ Wk,
                            const float* __restrict__ Wv, const float* __restrict__ Wo,
                            unsigned short* __restrict__ qn, unsigned short* __restrict__ kvn,
                            unsigned short* __restrict__ Wqb, unsigned short* __restrict__ Wkb,
                            unsigned short* __restrict__ Wvb, unsigned short* __restrict__ Wob) {
  int bx = blockIdx.x;
  if (bx < 256) {
    int widx = bx >> 6, blk = bx & 63;
    const float* src; unsigned short* dst;
    if (widx == 0)      { src = Wq; dst = Wqb; }
    else if (widx == 1) { src = Wk; dst = Wkb; }
    else if (widx == 2) { src = Wv; dst = Wvb; }
    else                { src = Wo; dst = Wob; }
    int i = (blk * 256 + threadIdx.x) * 4;
    float4 v = *(const float4*)(src + i);
    unsigned int lo = (unsigned int)f2bf(v.x) | ((unsigned int)f2bf(v.y) << 16);
    unsigned int hi = (unsigned int)f2bf(v.z) | ((unsigned int)f2bf(v.w) << 16);
    *(uint2*)(dst + i) = make_uint2(lo, hi);
    return;
  }
  int row = (bx - 256) * 64 + (threadIdx.x >> 2);
  int l4 = threadIdx.x & 3;
  const float* src; const float* ga; const float* be; unsigned short* dst;
  if (row < 2048) {
    src = q + (long)row * DM; ga = gq; be = bq; dst = qn + (long)row * DM;
  } else {
    int r2 = row - 2048;
    src = kv + (long)r2 * DM; ga = gkv; be = bkv; dst = kvn + (long)r2 * DM;
  }
  int c0 = l4 * 64;
  float s = 0.f, ss = 0.f;
  float4 xv[16];
#pragma unroll
  for (int i = 0; i < 16; i++) {
    float4 v = *(const float4*)(src + c0 + i * 4);
    xv[i] = v;
    s += v.x + v.y + v.z + v.w;
    ss += v.x * v.x + v.y * v.y + v.z * v.z + v.w * v.w;
  }
  s += __shfl_xor(s, 1, 4);  s += __shfl_xor(s, 2, 4);
  ss += __shfl_xor(ss, 1, 4); ss += __shfl_xor(ss, 2, 4);
  float mean = s * (1.0f / 256.0f);
  float var = ss * (1.0f / 256.0f) - mean * mean;
  float rs = 1.0f / sqrtf(var + 1e-5f);
#pragma unroll
  for (int i = 0; i < 8; i++) {
    float4 a = xv[2 * i], b = xv[2 * i + 1];
    float4 g0 = *(const float4*)(ga + c0 + i * 8);
    float4 g1 = *(const float4*)(ga + c0 + i * 8 + 4);
    float4 b0 = *(const float4*)(be + c0 + i * 8);
    float4 b1 = *(const float4*)(be + c0 + i * 8 + 4);
    unsigned short t[8];
    t[0] = f2bf((a.x - mean) * rs * g0.x + b0.x);
    t[1] = f2bf((a.y - mean) * rs * g0.y + b0.y);
    t[2] = f2bf((a.z - mean) * rs * g0.z + b0.z);
    t[3] = f2bf((a.w - mean) * rs * g0.w + b0.w);
    t[4] = f2bf((b.x - mean) * rs * g1.x + b1.x);
    t[5] = f2bf((b.y - mean) * rs * g1.y + b1.y);
    t[6] = f2bf((b.z - mean) * rs * g1.z + b1.z);
    t[7] = f2bf((b.w - mean) * rs * g1.w + b1.w);
    unsigned int u0 = (unsigned int)t[0] | ((unsigned int)t[1] << 16);
    unsigned int u1 = (unsigned int)t[2] | ((unsigned int)t[3] << 16);
    unsigned int u2 = (unsigned int)t[4] | ((unsigned int)t[5] << 16);
    unsigned int u3 = (unsigned int)t[6] | ((unsigned int)t[7] << 16);
    *(uint4*)(dst + c0 + i * 8) = make_uint4(u0, u1, u2, u3);
  }
}

// ---------------- all three projections, one dispatch ----------------
__global__ void proj_all_kernel(const unsigned short* __restrict__ qn, const unsigned short* __restrict__ kvn,
                                const unsigned short* __restrict__ Wqb, const unsigned short* __restrict__ Wkb,
                                const unsigned short* __restrict__ Wvb,
                                unsigned short* __restrict__ Qw, unsigned short* __restrict__ Kw,
                                unsigned short* __restrict__ Vtw) {
  int bx = blockIdx.x;
  const unsigned short* X; const unsigned short* Wb; unsigned short* out;
  int Nper, mode, mb;
  if (bx < 32)       { X = qn;  Wb = Wqb; out = Qw;  Nper = NQ;  mode = 0; mb = bx; }
  else if (bx < 288) { X = kvn; Wb = Wkb; out = Kw;  Nper = NKV; mode = 0; mb = bx - 32; }
  else               { X = kvn; Wb = Wvb; out = Vtw; Nper = NKV; mode = 1; mb = bx - 288; }

  int w = threadIdx.x >> 6, lane = threadIdx.x & 63;
  int c = lane & 15, g = lane >> 4;
  int mbase = mb * 64 + w * 16;
  f32x4 acc[16];
#pragma unroll
  for (int i = 0; i < 16; i++) acc[i] = (f32x4){0.f, 0.f, 0.f, 0.f};
  const unsigned short* arow = X + (long)(mbase + c) * DM + g * 8;
#pragma unroll
  for (int ks = 0; ks < 8; ks++) {
    bf16x8 af = *(const bf16x8*)(arow + ks * 32);
#pragma unroll
    for (int nt = 0; nt < 16; nt++) {
      bf16x8 bf = *(const bf16x8*)(Wb + (long)(nt * 16 + c) * DM + ks * 32 + g * 8);
      acc[nt] = __builtin_amdgcn_mfma_f32_16x16x32_bf16(af, bf, acc[nt], 0, 0, 0);
    }
  }
#pragma unroll
  for (int nt = 0; nt < 16; nt++) {
#pragma unroll
    for (int r = 0; r < 4; r++) {
      int m = mbase + 4 * g + r;
      int n = nt * 16 + c;
      int b = (m >= Nper) ? 1 : 0;
      int i = m - b * Nper;
      int h = n >> 5, dd = n & 31;
      long idx;
      if (mode == 0) idx = ((long)(b * H + h) * Nper + i) * DH + dd;
      else           idx = ((long)(b * H + h) * DH + dd) * (long)Nper + i;
      out[idx] = f2bf(acc[nt][r]);
    }
  }
}

// ---------------- flash attention: QBLK=128, 8 waves/block, s-interleaved chunks ----------------
// Bias loads are NON-TEMPORAL: the 537 MB stream has zero reuse and otherwise
// thrashes L3, evicting K/V (re-delivered 8x per head) and the Opart partials.
__global__ __launch_bounds__(512, 4) void attn_kernel(
    const unsigned short* __restrict__ Qw, const unsigned short* __restrict__ Kw,
    const unsigned short* __restrict__ Vtw, const float* __restrict__ bias,
    float* __restrict__ Opart, float* __restrict__ Mpart, float* __restrict__ Lpart) {
  __shared__ __align__(16) unsigned short Klds[KVBLK * 40];     // 10 KB
  __shared__ __align__(16) unsigned short Vlds[DH * 136];       // 8.5 KB
  __shared__ __align__(16) unsigned short Plds[8][16 * 136];    // 34.8 KB

  int bx = blockIdx.x;
  int s = bx & 7, qt = (bx >> 3) & 7, bh = bx >> 6;
  int tid = threadIdx.x;
  int w = tid >> 6, lane = tid & 63, c = lane & 15, g = lane >> 4;

  const f32x4 fzero = {0.f, 0.f, 0.f, 0.f};

  bf16x8 qfrag = *(const bf16x8*)(Qw + ((long)(bh * NQ + qt * QBLK + w * 16 + c)) * DH + g * 8);

  const float* brow = bias + ((long)bh * NQ + qt * QBLK + w * 16 + c) * (long)NKV + 4 * g;

  const unsigned short* Kbase = Kw + ((long)bh * NKV) * DH;    // [k][32]
  const unsigned short* Vbase = Vtw + ((long)bh * DH) * NKV;   // [d][NKV]

  float m_run = -1e30f;   // per-lane, q = c
  float l_run = 0.f;
  f32x4 oacc[2] = {fzero, fzero};

#pragma unroll 1
  for (int it = 0; it < NITER; it++) {
    int k0 = (it * KSPLIT + s) * KVBLK;   // interleaved chunk assignment

    // bias loads (contiguous f32x4 along k) — streaming / non-temporal
    f32x4 bfrag[8];
#pragma unroll
    for (int t = 0; t < 8; t++)
      bfrag[t] = __builtin_nontemporal_load((const f32x4*)(brow + k0 + t * 16));

    // stage K tile [128][32] -> Klds (pitch 40): 512 thr x 16B = 8 KB, one instr each
    {
      int krow = tid >> 2, kq4 = tid & 3;
      *(uint4*)(&Klds[krow * 40 + kq4 * 8]) =
          *(const uint4*)(Kbase + (long)(k0 + krow) * DH + kq4 * 8);
      // V^T tile [32][128] -> Vlds (pitch 136): one instr each
      int vd = tid >> 4, vq16 = tid & 15;
      *(uint4*)(&Vlds[vd * 136 + vq16 * 8]) =
          *(const uint4*)(Vbase + (long)vd * NKV + k0 + vq16 * 8);
    }
    __syncthreads();

    // S^T = K Q^T  (8 k-subtiles of 16)
    f32x4 sacc[8];
#pragma unroll
    for (int t = 0; t < 8; t++) {
      bf16x8 kf = *(const bf16x8*)(&Klds[(t * 16 + c) * 40 + g * 8]);
      sacc[t] = __builtin_amdgcn_mfma_f32_16x16x32_bf16(kf, qfrag, fzero, 0, 0, 0);
    }
#pragma unroll
    for (int t = 0; t < 8; t++) {
#pragma unroll
      for (int r = 0; r < 4; r++)
        sacc[t][r] = fmaf(sacc[t][r], SCALE, bfrag[t][r]);
    }

    // online softmax, per-lane row q=c
    float v = -1e30f;
#pragma unroll
    for (int t = 0; t < 8; t++)
      v = fmaxf(v, fmaxf(fmaxf(sacc[t][0], sacc[t][1]), fmaxf(sacc[t][2], sacc[t][3])));
    v = fmaxf(v, __shfl_xor(v, 16));
    v = fmaxf(v, __shfl_xor(v, 32));
    float mnew = fmaxf(m_run, v);
    float al = __expf(m_run - mnew);
    m_run = mnew;
    float rsum = 0.f;
#pragma unroll
    for (int t = 0; t < 8; t++) {
      float p0 = __expf(sacc[t][0] - mnew);
      float p1 = __expf(sacc[t][1] - mnew);
      float p2 = __expf(sacc[t][2] - mnew);
      float p3 = __expf(sacc[t][3] - mnew);
      rsum += (p0 + p1) + (p2 + p3);
      uint2 pk;
      pk.x = (unsigned int)f2bf(p0) | ((unsigned int)f2bf(p1) << 16);
      pk.y = (unsigned int)f2bf(p2) | ((unsigned int)f2bf(p3) << 16);
      *(uint2*)(&Plds[w][c * 136 + t * 16 + 4 * g]) = pk;
    }
    rsum += __shfl_xor(rsum, 16);
    rsum += __shfl_xor(rsum, 32);
    l_run = l_run * al + rsum;

    float alq[4];
#pragma unroll
    for (int r = 0; r < 4; r++) alq[r] = __shfl(al, 4 * g + r);
#pragma unroll
    for (int r = 0; r < 4; r++) { oacc[0][r] *= alq[r]; oacc[1][r] *= alq[r]; }

    // O += P @ V  (4 k-chunks of 32, 2 d-tiles of 16)
#pragma unroll
    for (int ch = 0; ch < 4; ch++) {
      bf16x8 pf = *(const bf16x8*)(&Plds[w][c * 136 + ch * 32 + g * 8]);
#pragma unroll
      for (int dt = 0; dt < 2; dt++) {
        bf16x8 vf = *(const bf16x8*)(&Vlds[(dt * 16 + c) * 136 + ch * 32 + g * 8]);
        oacc[dt] = __builtin_amdgcn_mfma_f32_16x16x32_bf16(pf, vf, oacc[dt], 0, 0, 0);
      }
    }
    __syncthreads();
  }
  // write partials (128 rows per block; row = w*16 + 4g+r, col = d)
  float* Op = Opart + (long)bx * (QBLK * 32);
#pragma unroll
  for (int dt = 0; dt < 2; dt++)
#pragma unroll
    for (int r = 0; r < 4; r++)
      Op[(w * 16 + 4 * g + r) * 32 + dt * 16 + c] = oacc[dt][r];
  if (g == 0) {
    Mpart[(long)bx * QBLK + w * 16 + c] = m_run;
    Lpart[(long)bx * QBLK + w * 16 + c] = l_run;
  }
}

// ---------------- fused merge + output projection + residual, 128 blocks ----------------
__global__ void merge_outproj_kernel(const float* __restrict__ Opart, const float* __restrict__ Mpart,
                                     const float* __restrict__ Lpart, const unsigned short* __restrict__ Wob,
                                     const float* __restrict__ qin, float* __restrict__ out) {
  __shared__ __align__(16) unsigned short OmT[16][264];

  int bx = blockIdx.x;
  int b = bx >> 6, t6 = bx & 63;
  int qt8 = t6 >> 3;                    // 128-row tile index
  int rbase = (t6 & 7) * 16;            // row offset within 128-row tile
  int tid = threadIdx.x;

  // ---- phase 1: merge ----
  int row16 = tid >> 4;                 // [0,16)
  int d0 = (tid & 15) * 2;              // [0,32) step 2
  int rowin = rbase + row16;
#pragma unroll 1
  for (int h = 0; h < 8; h++) {
    long pbase = (((long)(b * 8 + h) * 8 + qt8)) * 8;
    float mg = -1e30f, ms[8];
#pragma unroll
    for (int si = 0; si < 8; si++) {
      ms[si] = Mpart[(pbase + si) * QBLK + rowin];
      mg = fmaxf(mg, ms[si]);
    }
    float Lg = 0.f;
    float o0 = 0.f, o1 = 0.f;
#pragma unroll
    for (int si = 0; si < 8; si++) {
      float wsc = __expf(ms[si] - mg);
      Lg += Lpart[(pbase + si) * QBLK + rowin] * wsc;
      const float* op = Opart + (pbase + si) * (QBLK * 32) + rowin * 32 + d0;
      o0 += op[0] * wsc;
      o1 += op[1] * wsc;
    }
    float inv = 1.0f / Lg;
    unsigned int u = (unsigned int)f2bf(o0 * inv) | ((unsigned int)f2bf(o1 * inv) << 16);
    *(unsigned int*)(&OmT[row16][h * 32 + d0]) = u;
  }
  __syncthreads();

  // ---- phase 2: outproj + residual ----
  int w = tid >> 6, lane = tid & 63;
  int c = lane & 15, g = lane >> 4;
  long mglob = (long)b * NQ + t6 * 16;
  f32x4 acc[4];
#pragma unroll
  for (int i = 0; i < 4; i++) acc[i] = (f32x4){0.f, 0.f, 0.f, 0.f};
#pragma unroll
  for (int ks = 0; ks < 8; ks++) {
    bf16x8 af = *(const bf16x8*)(&OmT[c][ks * 32 + g * 8]);
#pragma unroll
    for (int j = 0; j < 4; j++) {
      int nt = w * 4 + j;
      bf16x8 bf = *(const bf16x8*)(Wob + (long)(nt * 16 + c) * DM + ks * 32 + g * 8);
      acc[j] = __builtin_amdgcn_mfma_f32_16x16x32_bf16(af, bf, acc[j], 0, 0, 0);
    }
  }
#pragma unroll
  for (int j = 0; j < 4; j++) {
#pragma unroll
    for (int r = 0; r < 4; r++) {
      long m = mglob + 4 * g + r;
      int n = (w * 4 + j) * 16 + c;
      out[m * DM + n] = qin[m * DM + n] + acc[j][r];
    }
  }
}

extern "C" void kernel_launch(void* const* d_in, const int* in_sizes, int n_in,
                              void* d_out, int out_size, void* d_ws, size_t ws_size,
                              hipStream_t stream) {
  (void)in_sizes; (void)n_in; (void)out_size; (void)ws_size;
  const float* q    = (const float*)d_in[0];
  const float* kv   = (const float*)d_in[1];
  const float* bias = (const float*)d_in[2];
  const float* Wq   = (const float*)d_in[3];
  const float* Wk   = (const float*)d_in[4];
  const float* Wv   = (const float*)d_in[5];
  const float* Wo   = (const float*)d_in[6];
  const float* gq   = (const float*)d_in[7];
  const float* bq   = (const float*)d_in[8];
  const float* gkv  = (const float*)d_in[9];
  const float* bkv  = (const float*)d_in[10];
  float* out = (float*)d_out;

  char* ws = (char*)d_ws;
  size_t off = 0;
  auto alloc = [&](size_t bytes) -> void* {
    void* p = ws + off;
    off += (bytes + 255) & ~(size_t)255;
    return p;
  };
  unsigned short* Wqb  = (unsigned short*)alloc(65536 * 2);
  unsigned short* Wkb  = (unsigned short*)alloc(65536 * 2);
  unsigned short* Wvb  = (unsigned short*)alloc(65536 * 2);
  unsigned short* Wob  = (unsigned short*)alloc(65536 * 2);
  unsigned short* qn   = (unsigned short*)alloc((size_t)2048 * 256 * 2);
  unsigned short* kvn  = (unsigned short*)alloc((size_t)16384 * 256 * 2);
  unsigned short* Qw   = (unsigned short*)alloc((size_t)2048 * 256 * 2);
  unsigned short* Kw   = (unsigned short*)alloc((size_t)16384 * 256 * 2);
  unsigned short* Vtw  = (unsigned short*)alloc((size_t)16384 * 256 * 2);
  float* Opart = (float*)alloc((size_t)1024 * 128 * 32 * 4);
  float* Mpart = (float*)alloc((size_t)1024 * 128 * 4);
  float* Lpart = (float*)alloc((size_t)1024 * 128 * 4);

  prep_kernel<<<544, 256, 0, stream>>>(q, kv, gq, bq, gkv, bkv, Wq, Wk, Wv, Wo,
                                       qn, kvn, Wqb, Wkb, Wvb, Wob);

  proj_all_kernel<<<544, 256, 0, stream>>>(qn, kvn, Wqb, Wkb, Wvb, Qw, Kw, Vtw);

  attn_kernel<<<1024, 512, 0, stream>>>(Qw, Kw, Vtw, bias, Opart, Mpart, Lpart);

  merge_outproj_kernel<<<128, 256, 0, stream>>>(Opart, Mpart, Lpart, Wob, q, out);
}

// Round 16
// 218.290 us; speedup vs baseline: 1.9529x; 1.0595x over previous
//
#include <hip/hip_runtime.h>
#include <hip/hip_bf16.h>
#include <stdint.h>

#define H 8
#define NQ 1024
#define NKV 8192
#define DM 256
#define DH 32
#define KVBLK 128
#define KSPLIT 8
#define QBLK 128
#define NITER (NKV / KSPLIT / KVBLK)   // 8
#define SCALE 0.17677669529663687f

typedef __attribute__((ext_vector_type(8))) __bf16 bf16x8;
typedef __attribute__((ext_vector_type(4))) float f32x4;

__device__ inline unsigned short f2bf(float f) {
  unsigned int u = __builtin_bit_cast(unsigned int, f);
  u = (u + 0x7FFFu + ((u >> 16) & 1u)) >> 16;
  return (unsigned short)u;
}

// ---------------- prep: weights fp32->bf16 (4x) + LayerNorm, one dispatch ----------------
__global__ void prep_kernel(const float* __restrict__ q, const float* __restrict__ kv,
                            const float* __restrict__ gq, const float* __restrict__ bq,
                            const float* __restrict__ gkv, const float* __restrict__ bkv,
                            const float* __restrict__ Wq, const float* __restrict__ Wk,
                            const float* __restrict__ Wv, const float* __restrict__ Wo,
                            unsigned short* __restrict__ qn, unsigned short* __restrict__ kvn,
                            unsigned short* __restrict__ Wqb, unsigned short* __restrict__ Wkb,
                            unsigned short* __restrict__ Wvb, unsigned short* __restrict__ Wob) {
  int bx = blockIdx.x;
  if (bx < 256) {
    int widx = bx >> 6, blk = bx & 63;
    const float* src; unsigned short* dst;
    if (widx == 0)      { src = Wq; dst = Wqb; }
    else if (widx == 1) { src = Wk; dst = Wkb; }
    else if (widx == 2) { src = Wv; dst = Wvb; }
    else                { src = Wo; dst = Wob; }
    int i = (blk * 256 + threadIdx.x) * 4;
    float4 v = *(const float4*)(src + i);
    unsigned int lo = (unsigned int)f2bf(v.x) | ((unsigned int)f2bf(v.y) << 16);
    unsigned int hi = (unsigned int)f2bf(v.z) | ((unsigned int)f2bf(v.w) << 16);
    *(uint2*)(dst + i) = make_uint2(lo, hi);
    return;
  }
  int row = (bx - 256) * 64 + (threadIdx.x >> 2);
  int l4 = threadIdx.x & 3;
  const float* src; const float* ga; const float* be; unsigned short* dst;
  if (row < 2048) {
    src = q + (long)row * DM; ga = gq; be = bq; dst = qn + (long)row * DM;
  } else {
    int r2 = row - 2048;
    src = kv + (long)r2 * DM; ga = gkv; be = bkv; dst = kvn + (long)r2 * DM;
  }
  int c0 = l4 * 64;
  float s = 0.f, ss = 0.f;
  float4 xv[16];
#pragma unroll
  for (int i = 0; i < 16; i++) {
    float4 v = *(const float4*)(src + c0 + i * 4);
    xv[i] = v;
    s += v.x + v.y + v.z + v.w;
    ss += v.x * v.x + v.y * v.y + v.z * v.z + v.w * v.w;
  }
  s += __shfl_xor(s, 1, 4);  s += __shfl_xor(s, 2, 4);
  ss += __shfl_xor(ss, 1, 4); ss += __shfl_xor(ss, 2, 4);
  float mean = s * (1.0f / 256.0f);
  float var = ss * (1.0f / 256.0f) - mean * mean;
  float rs = 1.0f / sqrtf(var + 1e-5f);
#pragma unroll
  for (int i = 0; i < 8; i++) {
    float4 a = xv[2 * i], b = xv[2 * i + 1];
    float4 g0 = *(const float4*)(ga + c0 + i * 8);
    float4 g1 = *(const float4*)(ga + c0 + i * 8 + 4);
    float4 b0 = *(const float4*)(be + c0 + i * 8);
    float4 b1 = *(const float4*)(be + c0 + i * 8 + 4);
    unsigned short t[8];
    t[0] = f2bf((a.x - mean) * rs * g0.x + b0.x);
    t[1] = f2bf((a.y - mean) * rs * g0.y + b0.y);
    t[2] = f2bf((a.z - mean) * rs * g0.z + b0.z);
    t[3] = f2bf((a.w - mean) * rs * g0.w + b0.w);
    t[4] = f2bf((b.x - mean) * rs * g1.x + b1.x);
    t[5] = f2bf((b.y - mean) * rs * g1.y + b1.y);
    t[6] = f2bf((b.z - mean) * rs * g1.z + b1.z);
    t[7] = f2bf((b.w - mean) * rs * g1.w + b1.w);
    unsigned int u0 = (unsigned int)t[0] | ((unsigned int)t[1] << 16);
    unsigned int u1 = (unsigned int)t[2] | ((unsigned int)t[3] << 16);
    unsigned int u2 = (unsigned int)t[4] | ((unsigned int)t[5] << 16);
    unsigned int u3 = (unsigned int)t[6] | ((unsigned int)t[7] << 16);
    *(uint4*)(dst + c0 + i * 8) = make_uint4(u0, u1, u2, u3);
  }
}

// ---------------- all three projections, one dispatch ----------------
__global__ void proj_all_kernel(const unsigned short* __restrict__ qn, const unsigned short* __restrict__ kvn,
                                const unsigned short* __restrict__ Wqb, const unsigned short* __restrict__ Wkb,
                                const unsigned short* __restrict__ Wvb,
                                unsigned short* __restrict__ Qw, unsigned short* __restrict__ Kw,
                                unsigned short* __restrict__ Vtw) {
  int bx = blockIdx.x;
  const unsigned short* X; const unsigned short* Wb; unsigned short* out;
  int Nper, mode, mb;
  if (bx < 32)       { X = qn;  Wb = Wqb; out = Qw;  Nper = NQ;  mode = 0; mb = bx; }
  else if (bx < 288) { X = kvn; Wb = Wkb; out = Kw;  Nper = NKV; mode = 0; mb = bx - 32; }
  else               { X = kvn; Wb = Wvb; out = Vtw; Nper = NKV; mode = 1; mb = bx - 288; }

  int w = threadIdx.x >> 6, lane = threadIdx.x & 63;
  int c = lane & 15, g = lane >> 4;
  int mbase = mb * 64 + w * 16;
  f32x4 acc[16];
#pragma unroll
  for (int i = 0; i < 16; i++) acc[i] = (f32x4){0.f, 0.f, 0.f, 0.f};
  const unsigned short* arow = X + (long)(mbase + c) * DM + g * 8;
#pragma unroll
  for (int ks = 0; ks < 8; ks++) {
    bf16x8 af = *(const bf16x8*)(arow + ks * 32);
#pragma unroll
    for (int nt = 0; nt < 16; nt++) {
      bf16x8 bf = *(const bf16x8*)(Wb + (long)(nt * 16 + c) * DM + ks * 32 + g * 8);
      acc[nt] = __builtin_amdgcn_mfma_f32_16x16x32_bf16(af, bf, acc[nt], 0, 0, 0);
    }
  }
#pragma unroll
  for (int nt = 0; nt < 16; nt++) {
#pragma unroll
    for (int r = 0; r < 4; r++) {
      int m = mbase + 4 * g + r;
      int n = nt * 16 + c;
      int b = (m >= Nper) ? 1 : 0;
      int i = m - b * Nper;
      int h = n >> 5, dd = n & 31;
      long idx;
      if (mode == 0) idx = ((long)(b * H + h) * Nper + i) * DH + dd;
      else           idx = ((long)(b * H + h) * DH + dd) * (long)Nper + i;
      out[idx] = f2bf(acc[nt][r]);
    }
  }
}

// ---------------- flash attention: QBLK=128, 8 waves/block, s-interleaved chunks ----------------
// K/V staged once per block serve 128 q-rows; the 8 co-resident s-blocks of one
// (bh,qt) read a contiguous 4KB run of every bias q-row each iteration (DRAM
// row locality). Proven best configuration (R12: 218.7 us).
__global__ __launch_bounds__(512, 4) void attn_kernel(
    const unsigned short* __restrict__ Qw, const unsigned short* __restrict__ Kw,
    const unsigned short* __restrict__ Vtw, const float* __restrict__ bias,
    float* __restrict__ Opart, float* __restrict__ Mpart, float* __restrict__ Lpart) {
  __shared__ __align__(16) unsigned short Klds[KVBLK * 40];     // 10 KB
  __shared__ __align__(16) unsigned short Vlds[DH * 136];       // 8.5 KB
  __shared__ __align__(16) unsigned short Plds[8][16 * 136];    // 34.8 KB

  int bx = blockIdx.x;
  int s = bx & 7, qt = (bx >> 3) & 7, bh = bx >> 6;
  int tid = threadIdx.x;
  int w = tid >> 6, lane = tid & 63, c = lane & 15, g = lane >> 4;

  const f32x4 fzero = {0.f, 0.f, 0.f, 0.f};

  bf16x8 qfrag = *(const bf16x8*)(Qw + ((long)(bh * NQ + qt * QBLK + w * 16 + c)) * DH + g * 8);

  const float* brow = bias + ((long)bh * NQ + qt * QBLK + w * 16 + c) * (long)NKV + 4 * g;

  const unsigned short* Kbase = Kw + ((long)bh * NKV) * DH;    // [k][32]
  const unsigned short* Vbase = Vtw + ((long)bh * DH) * NKV;   // [d][NKV]

  float m_run = -1e30f;   // per-lane, q = c
  float l_run = 0.f;
  f32x4 oacc[2] = {fzero, fzero};

#pragma unroll 1
  for (int it = 0; it < NITER; it++) {
    int k0 = (it * KSPLIT + s) * KVBLK;   // interleaved chunk assignment

    // bias loads (contiguous f32x4 along k)
    f32x4 bfrag[8];
#pragma unroll
    for (int t = 0; t < 8; t++)
      bfrag[t] = *(const f32x4*)(brow + k0 + t * 16);

    // stage K tile [128][32] -> Klds (pitch 40): 512 thr x 16B = 8 KB, one instr each
    {
      int krow = tid >> 2, kq4 = tid & 3;
      *(uint4*)(&Klds[krow * 40 + kq4 * 8]) =
          *(const uint4*)(Kbase + (long)(k0 + krow) * DH + kq4 * 8);
      // V^T tile [32][128] -> Vlds (pitch 136): one instr each
      int vd = tid >> 4, vq16 = tid & 15;
      *(uint4*)(&Vlds[vd * 136 + vq16 * 8]) =
          *(const uint4*)(Vbase + (long)vd * NKV + k0 + vq16 * 8);
    }
    __syncthreads();

    // S^T = K Q^T  (8 k-subtiles of 16)
    f32x4 sacc[8];
#pragma unroll
    for (int t = 0; t < 8; t++) {
      bf16x8 kf = *(const bf16x8*)(&Klds[(t * 16 + c) * 40 + g * 8]);
      sacc[t] = __builtin_amdgcn_mfma_f32_16x16x32_bf16(kf, qfrag, fzero, 0, 0, 0);
    }
#pragma unroll
    for (int t = 0; t < 8; t++) {
#pragma unroll
      for (int r = 0; r < 4; r++)
        sacc[t][r] = fmaf(sacc[t][r], SCALE, bfrag[t][r]);
    }

    // online softmax, per-lane row q=c
    float v = -1e30f;
#pragma unroll
    for (int t = 0; t < 8; t++)
      v = fmaxf(v, fmaxf(fmaxf(sacc[t][0], sacc[t][1]), fmaxf(sacc[t][2], sacc[t][3])));
    v = fmaxf(v, __shfl_xor(v, 16));
    v = fmaxf(v, __shfl_xor(v, 32));
    float mnew = fmaxf(m_run, v);
    float al = __expf(m_run - mnew);
    m_run = mnew;
    float rsum = 0.f;
#pragma unroll
    for (int t = 0; t < 8; t++) {
      float p0 = __expf(sacc[t][0] - mnew);
      float p1 = __expf(sacc[t][1] - mnew);
      float p2 = __expf(sacc[t][2] - mnew);
      float p3 = __expf(sacc[t][3] - mnew);
      rsum += (p0 + p1) + (p2 + p3);
      uint2 pk;
      pk.x = (unsigned int)f2bf(p0) | ((unsigned int)f2bf(p1) << 16);
      pk.y = (unsigned int)f2bf(p2) | ((unsigned int)f2bf(p3) << 16);
      *(uint2*)(&Plds[w][c * 136 + t * 16 + 4 * g]) = pk;
    }
    rsum += __shfl_xor(rsum, 16);
    rsum += __shfl_xor(rsum, 32);
    l_run = l_run * al + rsum;

    float alq[4];
#pragma unroll
    for (int r = 0; r < 4; r++) alq[r] = __shfl(al, 4 * g + r);
#pragma unroll
    for (int r = 0; r < 4; r++) { oacc[0][r] *= alq[r]; oacc[1][r] *= alq[r]; }

    // O += P @ V  (4 k-chunks of 32, 2 d-tiles of 16)
#pragma unroll
    for (int ch = 0; ch < 4; ch++) {
      bf16x8 pf = *(const bf16x8*)(&Plds[w][c * 136 + ch * 32 + g * 8]);
#pragma unroll
      for (int dt = 0; dt < 2; dt++) {
        bf16x8 vf = *(const bf16x8*)(&Vlds[(dt * 16 + c) * 136 + ch * 32 + g * 8]);
        oacc[dt] = __builtin_amdgcn_mfma_f32_16x16x32_bf16(pf, vf, oacc[dt], 0, 0, 0);
      }
    }
    __syncthreads();
  }
  // write partials (128 rows per block; row = w*16 + 4g+r, col = d)
  float* Op = Opart + (long)bx * (QBLK * 32);
#pragma unroll
  for (int dt = 0; dt < 2; dt++)
#pragma unroll
    for (int r = 0; r < 4; r++)
      Op[(w * 16 + 4 * g + r) * 32 + dt * 16 + c] = oacc[dt][r];
  if (g == 0) {
    Mpart[(long)bx * QBLK + w * 16 + c] = m_run;
    Lpart[(long)bx * QBLK + w * 16 + c] = l_run;
  }
}

// ---------------- fused merge + output projection + residual, 128 blocks ----------------
__global__ void merge_outproj_kernel(const float* __restrict__ Opart, const float* __restrict__ Mpart,
                                     const float* __restrict__ Lpart, const unsigned short* __restrict__ Wob,
                                     const float* __restrict__ qin, float* __restrict__ out) {
  __shared__ __align__(16) unsigned short OmT[16][264];

  int bx = blockIdx.x;
  int b = bx >> 6, t6 = bx & 63;
  int qt8 = t6 >> 3;                    // 128-row tile index
  int rbase = (t6 & 7) * 16;            // row offset within 128-row tile
  int tid = threadIdx.x;

  // ---- phase 1: merge ----
  int row16 = tid >> 4;                 // [0,16)
  int d0 = (tid & 15) * 2;              // [0,32) step 2
  int rowin = rbase + row16;
#pragma unroll 1
  for (int h = 0; h < 8; h++) {
    long pbase = (((long)(b * 8 + h) * 8 + qt8)) * 8;
    float mg = -1e30f, ms[8];
#pragma unroll
    for (int si = 0; si < 8; si++) {
      ms[si] = Mpart[(pbase + si) * QBLK + rowin];
      mg = fmaxf(mg, ms[si]);
    }
    float Lg = 0.f;
    float o0 = 0.f, o1 = 0.f;
#pragma unroll
    for (int si = 0; si < 8; si++) {
      float wsc = __expf(ms[si] - mg);
      Lg += Lpart[(pbase + si) * QBLK + rowin] * wsc;
      const float* op = Opart + (pbase + si) * (QBLK * 32) + rowin * 32 + d0;
      o0 += op[0] * wsc;
      o1 += op[1] * wsc;
    }
    float inv = 1.0f / Lg;
    unsigned int u = (unsigned int)f2bf(o0 * inv) | ((unsigned int)f2bf(o1 * inv) << 16);
    *(unsigned int*)(&OmT[row16][h * 32 + d0]) = u;
  }
  __syncthreads();

  // ---- phase 2: outproj + residual ----
  int w = tid >> 6, lane = tid & 63;
  int c = lane & 15, g = lane >> 4;
  long mglob = (long)b * NQ + t6 * 16;
  f32x4 acc[4];
#pragma unroll
  for (int i = 0; i < 4; i++) acc[i] = (f32x4){0.f, 0.f, 0.f, 0.f};
#pragma unroll
  for (int ks = 0; ks < 8; ks++) {
    bf16x8 af = *(const bf16x8*)(&OmT[c][ks * 32 + g * 8]);
#pragma unroll
    for (int j = 0; j < 4; j++) {
      int nt = w * 4 + j;
      bf16x8 bf = *(const bf16x8*)(Wob + (long)(nt * 16 + c) * DM + ks * 32 + g * 8);
      acc[j] = __builtin_amdgcn_mfma_f32_16x16x32_bf16(af, bf, acc[j], 0, 0, 0);
    }
  }
#pragma unroll
  for (int j = 0; j < 4; j++) {
#pragma unroll
    for (int r = 0; r < 4; r++) {
      long m = mglob + 4 * g + r;
      int n = (w * 4 + j) * 16 + c;
      out[m * DM + n] = qin[m * DM + n] + acc[j][r];
    }
  }
}

extern "C" void kernel_launch(void* const* d_in, const int* in_sizes, int n_in,
                              void* d_out, int out_size, void* d_ws, size_t ws_size,
                              hipStream_t stream) {
  (void)in_sizes; (void)n_in; (void)out_size; (void)ws_size;
  const float* q    = (const float*)d_in[0];
  const float* kv   = (const float*)d_in[1];
  const float* bias = (const float*)d_in[2];
  const float* Wq   = (const float*)d_in[3];
  const float* Wk   = (const float*)d_in[4];
  const float* Wv   = (const float*)d_in[5];
  const float* Wo   = (const float*)d_in[6];
  const float* gq   = (const float*)d_in[7];
  const float* bq   = (const float*)d_in[8];
  const float* gkv  = (const float*)d_in[9];
  const float* bkv  = (const float*)d_in[10];
  float* out = (float*)d_out;

  char* ws = (char*)d_ws;
  size_t off = 0;
  auto alloc = [&](size_t bytes) -> void* {
    void* p = ws + off;
    off += (bytes + 255) & ~(size_t)255;
    return p;
  };
  unsigned short* Wqb  = (unsigned short*)alloc(65536 * 2);
  unsigned short* Wkb  = (unsigned short*)alloc(65536 * 2);
  unsigned short* Wvb  = (unsigned short*)alloc(65536 * 2);
  unsigned short* Wob  = (unsigned short*)alloc(65536 * 2);
  unsigned short* qn   = (unsigned short*)alloc((size_t)2048 * 256 * 2);
  unsigned short* kvn  = (unsigned short*)alloc((size_t)16384 * 256 * 2);
  unsigned short* Qw   = (unsigned short*)alloc((size_t)2048 * 256 * 2);
  unsigned short* Kw   = (unsigned short*)alloc((size_t)16384 * 256 * 2);
  unsigned short* Vtw  = (unsigned short*)alloc((size_t)16384 * 256 * 2);
  float* Opart = (float*)alloc((size_t)1024 * 128 * 32 * 4);
  float* Mpart = (float*)alloc((size_t)1024 * 128 * 4);
  float* Lpart = (float*)alloc((size_t)1024 * 128 * 4);

  prep_kernel<<<544, 256, 0, stream>>>(q, kv, gq, bq, gkv, bkv, Wq, Wk, Wv, Wo,
                                       qn, kvn, Wqb, Wkb, Wvb, Wob);

  proj_all_kernel<<<544, 256, 0, stream>>>(qn, kvn, Wqb, Wkb, Wvb, Qw, Kw, Vtw);

  attn_kernel<<<1024, 512, 0, stream>>>(Qw, Kw, Vtw, bias, Opart, Mpart, Lpart);

  merge_outproj_kernel<<<128, 256, 0, stream>>>(Opart, Mpart, Lpart, Wob, q, out);
}